// Round 3
// baseline (1278.365 us; speedup 1.0000x reference)
//
#include <hip/hip_runtime.h>

// frames[T=3][Z=72][Y=512][X=1024], fp32.
#define TT 3
#define ZZ 72
#define YY 512
#define XX 1024
#define FRAME_STRIDE ((long)ZZ * YY * XX)
#define ZSTRIDE      ((long)YY * XX)
#define YSTRIDE      ((long)XX)

// Bucket key: z-major, then t, then y-tile (32 rows). z-major keeps all three
// frames' planes for a given z-window co-active -> frame 1 fetched once.
// t in the key makes the t1==t0 fast path wave-uniform.
#define YTILES 16                       // 512 / 32
#define NB (ZZ * TT * YTILES)           // 3456 buckets
#define PAD 16                          // uints per bucket slot = one 64B line (atomic spread)

#define HIST_BYTES ((size_t)NB * PAD * 4)

__device__ __forceinline__ int bucket_key(float4 c) {
    float t_abs = c.w * 3.0f;
    int t0 = min(max((int)floorf(t_abs), 0), TT - 1);
    int z0 = min(max((int)(c.x * (float)(ZZ - 1)), 0), ZZ - 1);
    int y0 = min(max((int)(c.y * (float)(YY - 1)), 0), YY - 1);
    return (z0 * TT + t0) * YTILES + (y0 >> 5);
}

__global__ __launch_bounds__(256) void hist_kernel(
    const float4* __restrict__ coords, unsigned* __restrict__ hist, int n)
{
    int i = blockIdx.x * blockDim.x + threadIdx.x;
    if (i >= n) return;
    atomicAdd(hist + bucket_key(coords[i]) * PAD, 1u);
}

__global__ __launch_bounds__(256) void scan_kernel(
    const unsigned* __restrict__ hist, unsigned* __restrict__ cursor)
{
    // single block of 256 threads; NB=3456 -> 14 per thread
    const int CH = (NB + 255) / 256;
    __shared__ unsigned part[256];
    int t = threadIdx.x;
    unsigned vals[CH];
    unsigned s = 0;
    for (int k = 0; k < CH; ++k) {
        int idx = t * CH + k;
        unsigned v = (idx < NB) ? hist[idx * PAD] : 0u;
        vals[k] = s;          // local exclusive prefix
        s += v;
    }
    part[t] = s;
    __syncthreads();
    for (int off = 1; off < 256; off <<= 1) {
        unsigned x = (t >= off) ? part[t - off] : 0u;
        __syncthreads();
        part[t] += x;
        __syncthreads();
    }
    unsigned base = (t == 0) ? 0u : part[t - 1];
    for (int k = 0; k < CH; ++k) {
        int idx = t * CH + k;
        if (idx < NB) cursor[idx * PAD] = base + vals[k];
    }
}

__global__ __launch_bounds__(256) void scatter_kernel(
    const float4* __restrict__ coords, unsigned* __restrict__ cursor,
    float4* __restrict__ sorted, unsigned* __restrict__ pos, int n)
{
    int i = blockIdx.x * blockDim.x + threadIdx.x;
    if (i >= n) return;
    float4 c = coords[i];
    unsigned slot = atomicAdd(cursor + bucket_key(c) * PAD, 1u);
    sorted[slot] = c;
    pos[i] = slot;
}

__device__ __forceinline__ float trilerp_frame(
    const float* __restrict__ fr,
    long oz0y0, long oz0y1, long oz1y0, long oz1y1,
    int x0, int x1, float wz, float wy, float wx)
{
    float c000 = fr[oz0y0 + x0];
    float c001 = fr[oz0y0 + x1];
    float c010 = fr[oz0y1 + x0];
    float c011 = fr[oz0y1 + x1];
    float c100 = fr[oz1y0 + x0];
    float c101 = fr[oz1y0 + x1];
    float c110 = fr[oz1y1 + x0];
    float c111 = fr[oz1y1 + x1];
    float iwx = 1.0f - wx;
    float c00 = c000 * iwx + c001 * wx;
    float c01 = c010 * iwx + c011 * wx;
    float c10 = c100 * iwx + c101 * wx;
    float c11 = c110 * iwx + c111 * wx;
    float iwy = 1.0f - wy;
    float c0 = c00 * iwy + c01 * wy;
    float c1 = c10 * iwy + c11 * wy;
    return c0 * (1.0f - wz) + c1 * wz;
}

__device__ __forceinline__ float interp_point(float4 c, const float* __restrict__ frames)
{
    float t_abs = c.w * 3.0f;
    int t0 = min(max((int)floorf(t_abs), 0), TT - 1);
    float w = t_abs - (float)t0;
    int t1 = min(t0 + 1, TT - 1);

    float sz = c.x * (float)(ZZ - 1);
    float sy = c.y * (float)(YY - 1);
    float sx = c.z * (float)(XX - 1);
    int z0 = (int)sz, y0 = (int)sy, x0 = (int)sx;
    float wz = sz - (float)z0;
    float wy = sy - (float)y0;
    float wx = sx - (float)x0;
    z0 = min(max(z0, 0), ZZ - 1);
    y0 = min(max(y0, 0), YY - 1);
    x0 = min(max(x0, 0), XX - 1);
    int z1 = min(z0 + 1, ZZ - 1);
    int y1 = min(y0 + 1, YY - 1);
    int x1 = min(x0 + 1, XX - 1);

    long oz0y0 = (long)z0 * ZSTRIDE + (long)y0 * YSTRIDE;
    long oz0y1 = (long)z0 * ZSTRIDE + (long)y1 * YSTRIDE;
    long oz1y0 = (long)z1 * ZSTRIDE + (long)y0 * YSTRIDE;
    long oz1y1 = (long)z1 * ZSTRIDE + (long)y1 * YSTRIDE;

    const float* f0 = frames + (long)t0 * FRAME_STRIDE;
    float v0 = trilerp_frame(f0, oz0y0, oz0y1, oz1y0, oz1y1, x0, x1, wz, wy, wx);
    float v1;
    if (t1 != t0) {   // wave-uniform after sort (t in bucket key)
        const float* f1 = frames + (long)t1 * FRAME_STRIDE;
        v1 = trilerp_frame(f1, oz0y0, oz0y1, oz1y0, oz1y1, x0, x1, wz, wy, wx);
    } else {
        v1 = v0;
    }
    return v0 * (1.0f - w) + v1 * w;
}

__global__ __launch_bounds__(256) void interp_sorted_kernel(
    const float4* __restrict__ sorted, const float* __restrict__ frames,
    float* __restrict__ tmp, int n)
{
    // XCD swizzle: give each XCD a contiguous chunk of the sorted array so its
    // private L2 sees one contiguous z-range (block->XCD mapping is blockIdx%8).
    int nb = gridDim.x;
    int b = blockIdx.x;
    int vb = b;
    if ((nb & 7) == 0) {
        int per = nb >> 3;
        vb = (b & 7) * per + (b >> 3);
    }
    int j = vb * blockDim.x + threadIdx.x;
    if (j >= n) return;
    tmp[j] = interp_point(sorted[j], frames);
}

__global__ __launch_bounds__(256) void unpermute_kernel(
    const float* __restrict__ tmp, const unsigned* __restrict__ pos,
    float* __restrict__ out, int n)
{
    int i = blockIdx.x * blockDim.x + threadIdx.x;
    if (i >= n) return;
    out[i] = tmp[pos[i]];   // scattered READ of 16MB (L2/L3-resident), coalesced write
}

// Fallback (direct, R2 kernel) if ws is too small.
__global__ __launch_bounds__(256) void interp_direct_kernel(
    const float4* __restrict__ coords, const float* __restrict__ frames,
    float* __restrict__ out, int n)
{
    int i = blockIdx.x * blockDim.x + threadIdx.x;
    if (i >= n) return;
    out[i] = interp_point(coords[i], frames);
}

extern "C" void kernel_launch(void* const* d_in, const int* in_sizes, int n_in,
                              void* d_out, int out_size, void* d_ws, size_t ws_size,
                              hipStream_t stream) {
    const float4* coords = (const float4*)d_in[0];
    const float*  frames = (const float*)d_in[1];
    float* out = (float*)d_out;
    int n = in_sizes[0] / 4;

    int block = 256;
    int grid = (n + block - 1) / block;

    // ws layout
    size_t off_hist   = 0;
    size_t off_cursor = off_hist + HIST_BYTES;
    size_t off_sorted = off_cursor + HIST_BYTES;
    size_t off_pos    = off_sorted + (size_t)n * sizeof(float4);
    size_t off_tmp    = off_pos + (size_t)n * sizeof(unsigned);
    size_t ws_needed  = off_tmp + (size_t)n * sizeof(float);

    if (ws_size < ws_needed) {
        interp_direct_kernel<<<grid, block, 0, stream>>>(coords, frames, out, n);
        return;
    }

    unsigned* hist   = (unsigned*)((char*)d_ws + off_hist);
    unsigned* cursor = (unsigned*)((char*)d_ws + off_cursor);
    float4*   sorted = (float4*)  ((char*)d_ws + off_sorted);
    unsigned* pos    = (unsigned*)((char*)d_ws + off_pos);
    float*    tmp    = (float*)   ((char*)d_ws + off_tmp);

    hipMemsetAsync(hist, 0, HIST_BYTES, stream);
    hist_kernel<<<grid, block, 0, stream>>>(coords, hist, n);
    scan_kernel<<<1, 256, 0, stream>>>(hist, cursor);
    scatter_kernel<<<grid, block, 0, stream>>>(coords, cursor, sorted, pos, n);
    interp_sorted_kernel<<<grid, block, 0, stream>>>(sorted, frames, tmp, n);
    unpermute_kernel<<<grid, block, 0, stream>>>(tmp, pos, out, n);
}